// Round 4
// baseline (1269.241 us; speedup 1.0000x reference)
//
#include <hip/hip_runtime.h>

#define N_PATHS 8192
#define T_STEPS 256
#define D_IN    44
#define H_SZ    8
#define G4      32      // 4*H
#define NGROUPS 1024
#define TC      16      // timesteps per chunk
#define NW      4       // waves per block
#define XG_STRIDE 164   // xg2 row stride: verified 0 bank conflicts (rounds 2-3)

// ---------------- workspace layout (floats) ----------------
// [0, 1408)            Wt   : W_ih transposed [d][g]
// [1408, 1440)         bias : b_ih + b_hh
// [1440, 1440+8192)    perm : path ids sorted by last_idx (int)
// [9632, 9632+8192)    s    : per-path score dot(h_last, fc_W)

__device__ __forceinline__ float sigm_f(float x) {
    return __builtin_amdgcn_rcpf(1.0f + __expf(-x));
}
__device__ __forceinline__ float tanh_f(float x) {
    return 1.0f - 2.0f * __builtin_amdgcn_rcpf(1.0f + __expf(2.0f * x));
}

// ---------------- prep: transpose weights + counting sort by last_idx ----------------
__global__ void prep_kernel(const float* __restrict__ W_ih, const float* __restrict__ b_ih,
                            const float* __restrict__ b_hh, const int* __restrict__ last_idx,
                            float* __restrict__ Wt, float* __restrict__ bias,
                            int* __restrict__ perm) {
    __shared__ int hist[256];
    __shared__ int off[256];
    const int tid = threadIdx.x;  // 256 threads
    hist[tid] = 0;
    for (int idx = tid; idx < G4 * D_IN; idx += 256) {
        int g = idx / D_IN, d = idx - g * D_IN;
        Wt[d * G4 + g] = W_ih[idx];
    }
    if (tid < G4) bias[tid] = b_ih[tid] + b_hh[tid];
    __syncthreads();
    for (int k = 0; k < N_PATHS / 256; ++k)
        atomicAdd(&hist[last_idx[k * 256 + tid]], 1);
    __syncthreads();
    if (tid == 0) {
        int run = 0;
        for (int i = 0; i < 256; ++i) { off[i] = run; run += hist[i]; }
    }
    __syncthreads();
    for (int k = 0; k < N_PATHS / 256; ++k) {
        int p = k * 256 + tid;
        int b = last_idx[p];
        int pos = atomicAdd(&off[b], 1);
        perm[pos] = p;
    }
}

// FMA one x element (xd = x[.,d]) against gate row d of WtL into the 8 float4 accs.
// All broadcast LDS reads (same addr across wave) -> conflict-free.
#define DSTEP(xd, d) { \
    const float4 wv0 = *(const float4*)&WtL[(d) * 32 +  0]; \
    const float4 wv1 = *(const float4*)&WtL[(d) * 32 +  4]; \
    const float4 wv2 = *(const float4*)&WtL[(d) * 32 +  8]; \
    const float4 wv3 = *(const float4*)&WtL[(d) * 32 + 12]; \
    const float4 wv4 = *(const float4*)&WtL[(d) * 32 + 16]; \
    const float4 wv5 = *(const float4*)&WtL[(d) * 32 + 20]; \
    const float4 wv6 = *(const float4*)&WtL[(d) * 32 + 24]; \
    const float4 wv7 = *(const float4*)&WtL[(d) * 32 + 28]; \
    a0.x = fmaf(wv0.x, (xd), a0.x); a0.y = fmaf(wv0.y, (xd), a0.y); \
    a0.z = fmaf(wv0.z, (xd), a0.z); a0.w = fmaf(wv0.w, (xd), a0.w); \
    a1.x = fmaf(wv1.x, (xd), a1.x); a1.y = fmaf(wv1.y, (xd), a1.y); \
    a1.z = fmaf(wv1.z, (xd), a1.z); a1.w = fmaf(wv1.w, (xd), a1.w); \
    a2.x = fmaf(wv2.x, (xd), a2.x); a2.y = fmaf(wv2.y, (xd), a2.y); \
    a2.z = fmaf(wv2.z, (xd), a2.z); a2.w = fmaf(wv2.w, (xd), a2.w); \
    a3.x = fmaf(wv3.x, (xd), a3.x); a3.y = fmaf(wv3.y, (xd), a3.y); \
    a3.z = fmaf(wv3.z, (xd), a3.z); a3.w = fmaf(wv3.w, (xd), a3.w); \
    a4.x = fmaf(wv4.x, (xd), a4.x); a4.y = fmaf(wv4.y, (xd), a4.y); \
    a4.z = fmaf(wv4.z, (xd), a4.z); a4.w = fmaf(wv4.w, (xd), a4.w); \
    a5.x = fmaf(wv5.x, (xd), a5.x); a5.y = fmaf(wv5.y, (xd), a5.y); \
    a5.z = fmaf(wv5.z, (xd), a5.z); a5.w = fmaf(wv5.w, (xd), a5.w); \
    a6.x = fmaf(wv6.x, (xd), a6.x); a6.y = fmaf(wv6.y, (xd), a6.y); \
    a6.z = fmaf(wv6.z, (xd), a6.z); a6.w = fmaf(wv6.w, (xd), a6.w); \
    a7.x = fmaf(wv7.x, (xd), a7.x); a7.y = fmaf(wv7.y, (xd), a7.y); \
    a7.z = fmaf(wv7.z, (xd), a7.z); a7.w = fmaf(wv7.w, (xd), a7.w); }

#define Q4(v, dbase) DSTEP((v).x, (dbase)) DSTEP((v).y, (dbase) + 1) \
                     DSTEP((v).z, (dbase) + 2) DSTEP((v).w, (dbase) + 3)

// ---------------- main fused LSTM kernel ----------------
// 256 threads = 4 independent waves; each wave owns 4 length-sorted paths.
// NO addressable locals in the hot path (named scalars only) -- round 2/3's
// float4 xb[11] was lowered to scratch => ~1 GB HBM read + 230 MB write.
__global__ __launch_bounds__(256, 3)
void lstm_kernel(const float* __restrict__ x, const float* __restrict__ Whh,
                 const float* __restrict__ Wt, const float* __restrict__ bias,
                 const float* __restrict__ fcW, const int* __restrict__ last_idx,
                 const int* __restrict__ perm, float* __restrict__ sout) {
    __shared__ float WtL[D_IN * G4];          // 5632 B, shared by all 4 waves
    __shared__ float biasL[G4];
    __shared__ float xg2[NW][TC][XG_STRIDE];  // per-wave gate buffer

    const int tid = threadIdx.x;
    const int w = tid >> 6;
    const int lane = tid & 63;
    const int gw = blockIdx.x * NW + w;       // global wave id, 0..2047

    for (int i = tid; i < D_IN * G4; i += 256) WtL[i] = Wt[i];
    if (tid < G4) biasL[tid] = bias[tid];
    __syncthreads();   // only block-wide barrier; waves independent afterwards

    const int p0 = perm[4 * gw + 0], p1 = perm[4 * gw + 1];
    const int p2 = perm[4 * gw + 2], p3 = perm[4 * gw + 3];
    const int l0 = last_idx[p0], l1 = last_idx[p1];
    const int l2 = last_idx[p2], l3 = last_idx[p3];
    const int wmax = max(max(l0, l1), max(l2, l3));

    // phase-1 ids: lane = tc1*4 + pl1
    const int pl1 = lane & 3, tc1 = lane >> 2;
    // phase-2 ids
    const int pl2 = lane >> 3, j = lane & 7;
    const bool act2 = lane < 32;

    const int pg1 = pl1 == 0 ? p0 : pl1 == 1 ? p1 : pl1 == 2 ? p2 : p3;
    const int pg2 = pl2 == 0 ? p0 : pl2 == 1 ? p1 : pl2 == 2 ? p2 : p3;
    const int lst2 = pl2 == 0 ? l0 : pl2 == 1 ? l1 : pl2 == 2 ? l2 : l3;

    // W_hh rows {j, 8+j, 16+j, 24+j} -> 8 named float4 (32 VGPRs, live whole kernel)
    const float4* whr0 = (const float4*)(Whh + (0 * 8 + j) * H_SZ);
    const float4* whr1 = (const float4*)(Whh + (1 * 8 + j) * H_SZ);
    const float4* whr2 = (const float4*)(Whh + (2 * 8 + j) * H_SZ);
    const float4* whr3 = (const float4*)(Whh + (3 * 8 + j) * H_SZ);
    const float4 wh00 = whr0[0], wh01 = whr0[1];
    const float4 wh10 = whr1[0], wh11 = whr1[1];
    const float4 wh20 = whr2[0], wh21 = whr2[1];
    const float4 wh30 = whr3[0], wh31 = whr3[1];
    const float fcWj = fcW[j];

    float hval = 0.f, cval = 0.f, hlast = 0.f;

    const float* xrow = x + (size_t)pg1 * (T_STEPS * D_IN) + tc1 * D_IN;
    const int nch = (wmax >> 4) + 1;
    const int sbase = lane & ~7;   // 8-lane all-gather base
    float* const xgout = &xg2[w][tc1][pl1 * 40];

    for (int ch = 0; ch < nch; ++ch) {
        // ---------------- phase 1: xg = bias + x . Wt ----------------
        {
            const float4* xr = (const float4*)(xrow + ch * (TC * D_IN));
            // 11 independent loads, named scalars (one memory latency, no scratch)
            const float4 xv0 = xr[0], xv1 = xr[1], xv2 = xr[2], xv3 = xr[3];
            const float4 xv4 = xr[4], xv5 = xr[5], xv6 = xr[6], xv7 = xr[7];
            const float4 xv8 = xr[8], xv9 = xr[9], xv10 = xr[10];

            float4 a0 = *(const float4*)&biasL[0];
            float4 a1 = *(const float4*)&biasL[4];
            float4 a2 = *(const float4*)&biasL[8];
            float4 a3 = *(const float4*)&biasL[12];
            float4 a4 = *(const float4*)&biasL[16];
            float4 a5 = *(const float4*)&biasL[20];
            float4 a6 = *(const float4*)&biasL[24];
            float4 a7 = *(const float4*)&biasL[28];

            Q4(xv0, 0)  Q4(xv1, 4)  Q4(xv2, 8)  Q4(xv3, 12)
            Q4(xv4, 16) Q4(xv5, 20) Q4(xv6, 24) Q4(xv7, 28)
            Q4(xv8, 32) Q4(xv9, 36) Q4(xv10, 40)

            *(float4*)(xgout + 0)  = a0;
            *(float4*)(xgout + 4)  = a1;
            *(float4*)(xgout + 8)  = a2;
            *(float4*)(xgout + 12) = a3;
            *(float4*)(xgout + 16) = a4;
            *(float4*)(xgout + 20) = a5;
            *(float4*)(xgout + 24) = a6;
            *(float4*)(xgout + 28) = a7;
        }

        // ---------------- phase 2: 16 recurrence steps ----------------
        if (act2) {
            const int t0 = ch * TC;
#pragma unroll
            for (int tt = 0; tt < TC; ++tt) {
                const float h0 = __shfl(hval, sbase + 0);
                const float h1 = __shfl(hval, sbase + 1);
                const float h2 = __shfl(hval, sbase + 2);
                const float h3 = __shfl(hval, sbase + 3);
                const float h4 = __shfl(hval, sbase + 4);
                const float h5 = __shfl(hval, sbase + 5);
                const float h6 = __shfl(hval, sbase + 6);
                const float h7 = __shfl(hval, sbase + 7);
                const float* xr2 = &xg2[w][tt][pl2 * 40 + j];
                float pi = xr2[0], pf = xr2[8], pg = xr2[16], po = xr2[24];
                pi = fmaf(wh00.x, h0, pi); pi = fmaf(wh00.y, h1, pi);
                pi = fmaf(wh00.z, h2, pi); pi = fmaf(wh00.w, h3, pi);
                pi = fmaf(wh01.x, h4, pi); pi = fmaf(wh01.y, h5, pi);
                pi = fmaf(wh01.z, h6, pi); pi = fmaf(wh01.w, h7, pi);
                pf = fmaf(wh10.x, h0, pf); pf = fmaf(wh10.y, h1, pf);
                pf = fmaf(wh10.z, h2, pf); pf = fmaf(wh10.w, h3, pf);
                pf = fmaf(wh11.x, h4, pf); pf = fmaf(wh11.y, h5, pf);
                pf = fmaf(wh11.z, h6, pf); pf = fmaf(wh11.w, h7, pf);
                pg = fmaf(wh20.x, h0, pg); pg = fmaf(wh20.y, h1, pg);
                pg = fmaf(wh20.z, h2, pg); pg = fmaf(wh20.w, h3, pg);
                pg = fmaf(wh21.x, h4, pg); pg = fmaf(wh21.y, h5, pg);
                pg = fmaf(wh21.z, h6, pg); pg = fmaf(wh21.w, h7, pg);
                po = fmaf(wh30.x, h0, po); po = fmaf(wh30.y, h1, po);
                po = fmaf(wh30.z, h2, po); po = fmaf(wh30.w, h3, po);
                po = fmaf(wh31.x, h4, po); po = fmaf(wh31.y, h5, po);
                po = fmaf(wh31.z, h6, po); po = fmaf(wh31.w, h7, po);
                const float ig = sigm_f(pi);
                const float fg = sigm_f(pf);
                const float gg = tanh_f(pg);
                const float og = sigm_f(po);
                cval = fmaf(fg, cval, ig * gg);
                hval = og * tanh_f(cval);
                hlast = ((t0 + tt) == lst2) ? hval : hlast;
            }
        }
    }

    if (act2) {
        float v = hlast * fcWj;            // per-path score = dot(h_last, fc_W)
        v += __shfl_xor(v, 1);
        v += __shfl_xor(v, 2);
        v += __shfl_xor(v, 4);
        if (j == 0) sout[pg2] = v;
    }
}

// ---------------- finalize: segment-sum + softmax over 1024 groups ----------------
__global__ void finalize_kernel(const float* __restrict__ s, const int* __restrict__ gid,
                                float* __restrict__ out) {
    __shared__ float seg[NGROUPS];
    __shared__ float red[16];
    const int tid = threadIdx.x;  // 1024
    seg[tid] = 0.f;
    __syncthreads();
#pragma unroll
    for (int k = 0; k < 8; ++k) {
        const int p = k * 1024 + tid;
        atomicAdd(&seg[gid[p]], s[p]);
    }
    __syncthreads();
    const float v = seg[tid];  // logit (fc_b cancels exactly in softmax)
    const int wid = tid >> 6, ln = tid & 63;
    float m = v;
#pragma unroll
    for (int o = 32; o >= 1; o >>= 1) m = fmaxf(m, __shfl_xor(m, o));
    if (ln == 0) red[wid] = m;
    __syncthreads();
    if (tid < 16) {
        float mm = red[tid];
#pragma unroll
        for (int o = 8; o >= 1; o >>= 1) mm = fmaxf(mm, __shfl_xor(mm, o));
        red[tid] = mm;
    }
    __syncthreads();
    const float vmax = red[0];
    __syncthreads();
    const float e = __expf(v - vmax);
    float ss = e;
#pragma unroll
    for (int o = 32; o >= 1; o >>= 1) ss += __shfl_xor(ss, o);
    if (ln == 0) red[wid] = ss;
    __syncthreads();
    if (tid < 16) {
        float s2 = red[tid];
#pragma unroll
        for (int o = 8; o >= 1; o >>= 1) s2 += __shfl_xor(s2, o);
        red[tid] = s2;
    }
    __syncthreads();
    const float tot = red[0];
    out[tid] = e / tot;
}

extern "C" void kernel_launch(void* const* d_in, const int* in_sizes, int n_in,
                              void* d_out, int out_size, void* d_ws, size_t ws_size,
                              hipStream_t stream) {
    const float* x      = (const float*)d_in[0];
    const float* W_ih   = (const float*)d_in[1];
    const float* W_hh   = (const float*)d_in[2];
    const float* b_ih   = (const float*)d_in[3];
    const float* b_hh   = (const float*)d_in[4];
    const float* fcW    = (const float*)d_in[5];
    // d_in[6] = fc_b: cancels in softmax
    const int* last_idx = (const int*)d_in[7];
    const int* gid      = (const int*)d_in[8];

    float* wsf  = (float*)d_ws;
    float* Wt   = wsf;
    float* bias = wsf + 1408;
    int*   perm = (int*)(wsf + 1440);
    float* sarr = wsf + 1440 + 8192;
    float* out  = (float*)d_out;

    hipLaunchKernelGGL(prep_kernel, dim3(1), dim3(256), 0, stream,
                       W_ih, b_ih, b_hh, last_idx, Wt, bias, perm);
    hipLaunchKernelGGL(lstm_kernel, dim3(N_PATHS / (4 * NW)), dim3(64 * NW), 0, stream,
                       x, W_hh, Wt, bias, fcW, last_idx, perm, sarr);
    hipLaunchKernelGGL(finalize_kernel, dim3(1), dim3(1024), 0, stream,
                       sarr, gid, out);
}